// Round 13
// baseline (374.674 us; speedup 1.0000x reference)
//
#include <hip/hip_runtime.h>
#include <hip/hip_fp16.h>

// RGCN 2-layer fused, MI355X. dst-CSR built once per call.
// R13: int4-vectorized deg_rank (4 edges/thread, 8 atomics in flight) and
// scatter_csr; cvt_relw folded into prescale. fp16 feature storage (halves
// gather lines; validated r12, absmax 3.9e-3). fp32 accumulation throughout.

#define SCAN_BLK 1024

// 4 edges/thread: rank[e] = arrival index within dst bucket; counts degrees.
__global__ void deg_rank_kernel(const int4* __restrict__ src4, const int4* __restrict__ dst4,
                                int* __restrict__ out_cnt, int* __restrict__ in_cnt,
                                int4* __restrict__ rank4, int E4) {
  int q = blockIdx.x * blockDim.x + threadIdx.x;
  int stride = gridDim.x * blockDim.x;
  for (; q < E4; q += stride) {
    const int4 s = src4[q];
    const int4 d = dst4[q];
    int4 r;
    r.x = atomicAdd(&in_cnt[d.x], 1);
    r.y = atomicAdd(&in_cnt[d.y], 1);
    r.z = atomicAdd(&in_cnt[d.z], 1);
    r.w = atomicAdd(&in_cnt[d.w], 1);
    atomicAdd(&out_cnt[s.x], 1);
    atomicAdd(&out_cnt[s.y], 1);
    atomicAdd(&out_cnt[s.z], 1);
    atomicAdd(&out_cnt[s.w], 1);
    rank4[q] = r;
  }
}

// scalar tail (E % 4 edges)
__global__ void deg_rank_tail(const int* __restrict__ src, const int* __restrict__ dst,
                              int* __restrict__ out_cnt, int* __restrict__ in_cnt,
                              int* __restrict__ rank, int e0, int E) {
  int e = e0 + blockIdx.x * blockDim.x + threadIdx.x;
  if (e < E) {
    rank[e] = atomicAdd(&in_cnt[dst[e]], 1);
    atomicAdd(&out_cnt[src[e]], 1);
  }
}

// Per-block inclusive scan of in_cnt -> rowptr[i+1] (block-local); block sums out.
__global__ void scan_a(const int* __restrict__ in, int* __restrict__ out1,
                       int* __restrict__ bsums, int n) {
  __shared__ int tmp[SCAN_BLK];
  int i = blockIdx.x * SCAN_BLK + threadIdx.x;
  tmp[threadIdx.x] = (i < n) ? in[i] : 0;
  __syncthreads();
  for (int off = 1; off < SCAN_BLK; off <<= 1) {
    int t = (threadIdx.x >= off) ? tmp[threadIdx.x - off] : 0;
    __syncthreads();
    tmp[threadIdx.x] += t;
    __syncthreads();
  }
  if (i < n) out1[i] = tmp[threadIdx.x];
  if (threadIdx.x == SCAN_BLK - 1) bsums[blockIdx.x] = tmp[SCAN_BLK - 1];
}

// Parallel exclusive scan of block sums (nb <= 256), single block.
__global__ void scan_b(const int* __restrict__ bsums, int* __restrict__ boff, int nb) {
  __shared__ int t[256];
  int v = (threadIdx.x < nb) ? bsums[threadIdx.x] : 0;
  t[threadIdx.x] = v;
  __syncthreads();
  for (int off = 1; off < 256; off <<= 1) {
    int u = (threadIdx.x >= off) ? t[threadIdx.x - off] : 0;
    __syncthreads();
    t[threadIdx.x] += u;
    __syncthreads();
  }
  if (threadIdx.x < nb) boff[threadIdx.x] = t[threadIdx.x] - v;  // exclusive
}

// Fused: finalize rowptr into rowfin (race-free separate array) + norms.
// nrm4[i] = {inv_in, sq_out, norm_in, norm_out}.
__global__ void scan_c2(const int* __restrict__ rowptr, const int* __restrict__ boff,
                        const int* __restrict__ out_cnt, const int* __restrict__ in_cnt,
                        int* __restrict__ rowfin, float4* __restrict__ nrm4, int n) {
  int i = blockIdx.x * blockDim.x + threadIdx.x;
  if (i < n) {
    rowfin[i + 1] = rowptr[i + 1] + boff[i >> 10];
    if (i == 0) rowfin[0] = 0;
    float od = (float)max(out_cnt[i], 1);
    float id = (float)max(in_cnt[i], 1);
    float4 v;
    v.x = 1.0f / id;      // inv_in
    v.y = sqrtf(od);      // sq_out
    v.z = rsqrtf(id);     // norm_in
    v.w = rsqrtf(od);     // norm_out
    nrm4[i] = v;
  }
}

// load 4 packed halves -> float4
__device__ inline float4 ldh4(const uint2* __restrict__ p, size_t idx) {
  const uint2 v = p[idx];
  const __half2 a = *reinterpret_cast<const __half2*>(&v.x);
  const __half2 b = *reinterpret_cast<const __half2*>(&v.y);
  const float2 fa = __half22float2(a);
  const float2 fb = __half22float2(b);
  return make_float4(fa.x, fa.y, fb.x, fb.y);
}

__device__ inline uint2 pkh4(float a, float b, float c, float d) {
  __half2 h01 = __floats2half2_rn(a, b);
  __half2 h23 = __floats2half2_rn(c, d);
  uint2 o;
  o.x = *reinterpret_cast<unsigned int*>(&h01);
  o.y = *reinterpret_cast<unsigned int*>(&h23);
  return o;
}

// Fused: xs_h = half(x * norm_out) for i<n16; relw fp32->fp16 for the tail.
__global__ void prescale_h(const float4* __restrict__ x4, const float4* __restrict__ nrm4,
                           uint2* __restrict__ xsh,
                           const float4* __restrict__ rw4, uint2* __restrict__ rwh,
                           int n16, int nrw4) {
  int i = blockIdx.x * blockDim.x + threadIdx.x;
  if (i < n16) {
    float no = nrm4[i >> 4].w;
    float4 v = x4[i];
    xsh[i] = pkh4(v.x * no, v.y * no, v.z * no, v.w * no);
  } else if (i - n16 < nrw4) {
    int j = i - n16;
    float4 v = rw4[j];
    rwh[j] = pkh4(v.x, v.y, v.z, v.w);
  }
}

// Atomic-free CSR fill, 4 edges/thread: slot = rowfin[dst]+rank (unique).
__global__ void scatter_csr(const int4* __restrict__ src4, const int4* __restrict__ dst4,
                            const int4* __restrict__ et4, const int4* __restrict__ rank4,
                            const int* __restrict__ rowfin, int* __restrict__ ce, int E4) {
  int q = blockIdx.x * blockDim.x + threadIdx.x;
  int stride = gridDim.x * blockDim.x;
  for (; q < E4; q += stride) {
    const int4 s = src4[q];
    const int4 d = dst4[q];
    const int4 t = et4[q];
    const int4 r = rank4[q];
    ce[rowfin[d.x] + r.x] = s.x | (t.x << 20);
    ce[rowfin[d.y] + r.y] = s.y | (t.y << 20);
    ce[rowfin[d.z] + r.z] = s.z | (t.z << 20);
    ce[rowfin[d.w] + r.w] = s.w | (t.w << 20);
  }
}

__global__ void scatter_tail(const int* __restrict__ src, const int* __restrict__ dst,
                             const int* __restrict__ et, const int* __restrict__ rank,
                             const int* __restrict__ rowfin, int* __restrict__ ce,
                             int e0, int E) {
  int e = e0 + blockIdx.x * blockDim.x + threadIdx.x;
  if (e < E) ce[rowfin[dst[e]] + rank[e]] = src[e] | (et[e] << 20);
}

// Self-loop GEMM: y[node][lane] = (xs[node,:] . W[:,lane]) * sq_out[node].
// Wave = node (grid-stride). W column in 64 VGPRs; xs rows read fp16 uniform.
__launch_bounds__(256, 4)
__global__ void selfloop_kernel(const uint2* __restrict__ xsh, const float* __restrict__ W,
                                const float4* __restrict__ nrm4,
                                float* __restrict__ y, int n) {
  const int lane = threadIdx.x & 63;
  float wc[64];
#pragma unroll
  for (int k = 0; k < 64; ++k) wc[k] = W[k * 64 + lane];   // coalesced
  const int wid = (blockIdx.x * blockDim.x + threadIdx.x) >> 6;
  const int nw = (gridDim.x * blockDim.x) >> 6;
  for (int node0 = wid; node0 < n; node0 += nw) {
    const int node = __builtin_amdgcn_readfirstlane(node0);
    const uint2* __restrict__ xr = xsh + (size_t)node * 16;
    float d0 = 0.f, d1 = 0.f, d2 = 0.f, d3 = 0.f;
#pragma unroll
    for (int kk = 0; kk < 16; ++kk) {
      const float4 v = ldh4(xr, kk);
      const int k = kk << 2;
      d0 = fmaf(v.x, wc[k],     d0);
      d1 = fmaf(v.y, wc[k + 1], d1);
      d2 = fmaf(v.z, wc[k + 2], d2);
      d3 = fmaf(v.w, wc[k + 3], d3);
    }
    y[(size_t)node * 64 + lane] = ((d0 + d1) + (d2 + d3)) * nrm4[node].y;
  }
}

// Edge-only RGCN layer, fp16 gathers. Wave = 1 node. Groups g=0..3 (16 lanes),
// lane owns cols 4l..4l+3 (uint2 = 4 halves), edges strided by group, unroll
// x2. Butterfly-reduce + transpose to col=lane, add self-loop row y (fp32),
// norms, relu. Output: fp16 (hidden) or fp32 (final).
template <bool FINAL>
__launch_bounds__(256, 8)
__global__ void layer_kernel(const uint2* __restrict__ xsh, const float* __restrict__ y,
                             const uint2* __restrict__ rwh,
                             const int* __restrict__ rowptr, const int* __restrict__ ce,
                             const float4* __restrict__ nrm4,
                             void* __restrict__ xout, int n) {
  const int node = blockIdx.x * 4 + (threadIdx.x >> 6);
  if (node >= n) return;
  const int lane = threadIdx.x & 63;
  const int g = lane >> 4;
  const int l = lane & 15;

  const int rb = rowptr[node];
  const int re = rowptr[node + 1];
  const float4 nr = nrm4[node];  // {inv_in, sq_out, norm_in, norm_out}

  // ---- edge aggregation: group g takes edges rb+g, rb+g+4, ...; unroll x2 ----
  float4 acc0 = {0.f, 0.f, 0.f, 0.f};
  float4 acc1 = {0.f, 0.f, 0.f, 0.f};
  int e = rb + g;
  for (; e + 4 < re; e += 8) {
    const int p0 = ce[e];
    const int p1 = ce[e + 4];
    const int s0 = p0 & 0xFFFFF, t0 = p0 >> 20;
    const int s1 = p1 & 0xFFFFF, t1 = p1 >> 20;
    const float4 xv0 = ldh4(xsh, (size_t)s0 * 16 + l);
    const float4 xv1 = ldh4(xsh, (size_t)s1 * 16 + l);
    const float4 rv0 = ldh4(rwh, t0 * 16 + l);
    const float4 rv1 = ldh4(rwh, t1 * 16 + l);
    acc0.x = fmaf(xv0.x, rv0.x, acc0.x);
    acc0.y = fmaf(xv0.y, rv0.y, acc0.y);
    acc0.z = fmaf(xv0.z, rv0.z, acc0.z);
    acc0.w = fmaf(xv0.w, rv0.w, acc0.w);
    acc1.x = fmaf(xv1.x, rv1.x, acc1.x);
    acc1.y = fmaf(xv1.y, rv1.y, acc1.y);
    acc1.z = fmaf(xv1.z, rv1.z, acc1.z);
    acc1.w = fmaf(xv1.w, rv1.w, acc1.w);
  }
  if (e < re) {
    const int p = ce[e];
    const int s = p & 0xFFFFF, t = p >> 20;
    const float4 xv = ldh4(xsh, (size_t)s * 16 + l);
    const float4 rv = ldh4(rwh, t * 16 + l);
    acc0.x = fmaf(xv.x, rv.x, acc0.x);
    acc0.y = fmaf(xv.y, rv.y, acc0.y);
    acc0.z = fmaf(xv.z, rv.z, acc0.z);
    acc0.w = fmaf(xv.w, rv.w, acc0.w);
  }
  float4 pre;
  pre.x = acc0.x + acc1.x;
  pre.y = acc0.y + acc1.y;
  pre.z = acc0.z + acc1.z;
  pre.w = acc0.w + acc1.w;

  // butterfly-reduce across the 4 groups (result lands in ALL lanes)
  pre.x += __shfl_xor(pre.x, 16); pre.x += __shfl_xor(pre.x, 32);
  pre.y += __shfl_xor(pre.y, 16); pre.y += __shfl_xor(pre.y, 32);
  pre.z += __shfl_xor(pre.z, 16); pre.z += __shfl_xor(pre.z, 32);
  pre.w += __shfl_xor(pre.w, 16); pre.w += __shfl_xor(pre.w, 32);

  // transpose float4-per-16lane -> scalar col=lane
  const int srcl = lane >> 2;
  const float t0 = __shfl(pre.x, srcl);
  const float t1 = __shfl(pre.y, srcl);
  const float t2 = __shfl(pre.z, srcl);
  const float t3 = __shfl(pre.w, srcl);
  const float ea = (lane & 2) ? ((lane & 1) ? t3 : t2)
                              : ((lane & 1) ? t1 : t0);

  // self-loop row (precomputed, already * sq_out): coalesced b32
  const float yv = y[(size_t)node * 64 + lane];

  // relu(a)*c == relu(a*c) for c>0: fold norm_in (and norm_out if !FINAL)
  const float scale = FINAL ? nr.z : nr.z * nr.w;
  const float r = fmaxf(fmaf(ea, nr.x, yv) * scale, 0.f);
  if (FINAL) {
    ((float*)xout)[(size_t)node * 64 + lane] = r;
  } else {
    ((__half*)xout)[(size_t)node * 64 + lane] = __float2half_rn(r);
  }
}

extern "C" void kernel_launch(void* const* d_in, const int* in_sizes, int n_in,
                              void* d_out, int out_size, void* d_ws, size_t ws_size,
                              hipStream_t stream) {
  const float* x     = (const float*)d_in[0];
  const float* relw  = (const float*)d_in[1];
  const float* w1    = (const float*)d_in[2];
  const float* w2    = (const float*)d_in[3];
  const int*   src   = (const int*)d_in[4];
  const int*   dst   = (const int*)d_in[5];
  const int*   etype = (const int*)d_in[6];

  const int N = in_sizes[0] / 64;
  const int E = in_sizes[4];
  const int R4 = in_sizes[1] / 4;   // relw float4 count (50*64/4 = 800)
  const int E4 = E >> 2;            // full int4 quads
  const int Etail = E & 3;

  char* w = (char*)d_ws;
  size_t off = 0;
  auto alloc = [&](size_t bytes) -> void* {
    void* p = w + off;
    off = (off + bytes + 255) & ~(size_t)255;
    return p;
  };
  int*    out_cnt = (int*)alloc((size_t)N * 4);     // zeroed (contiguous with in_cnt)
  int*    in_cnt  = (int*)alloc((size_t)N * 4);
  int*    rowptr  = (int*)alloc((size_t)(N + 1) * 4);   // partial (scan_a output)
  int*    rowfin  = (int*)alloc((size_t)(N + 1) * 4);   // final CSR rowptr
  float4* nrm4    = (float4*)alloc((size_t)N * 16);
  int*    bsums   = (int*)alloc(256 * 4);
  int*    boff    = (int*)alloc(256 * 4);
  int*    rank    = (int*)alloc((size_t)(E4 + 1) * 16); // in-bucket arrival rank (int4-aligned)
  int*    ce      = (int*)alloc((size_t)E * 4);     // packed src|etype<<20
  uint2*  rwh     = (uint2*)alloc((size_t)R4 * 8);  // relw fp16 packed
  uint2*  xsh     = (uint2*)alloc((size_t)N * 16 * 8);  // fp16 prescaled input
  uint2*  h1h     = (uint2*)alloc((size_t)N * 16 * 8);  // fp16 hidden layer
  float*  y       = (float*)alloc((size_t)N * 64 * 4);  // self-loop rows (fp32)

  // zero the two degree arrays (contiguous in ws)
  hipMemsetAsync(out_cnt, 0, ((char*)rowptr - (char*)out_cnt), stream);

  const int nb = (N + SCAN_BLK - 1) / SCAN_BLK;

  deg_rank_kernel<<<(E4 + 255) / 256, 256, 0, stream>>>(
      (const int4*)src, (const int4*)dst, out_cnt, in_cnt, (int4*)rank, E4);
  if (Etail)
    deg_rank_tail<<<1, 64, 0, stream>>>(src, dst, out_cnt, in_cnt, rank, E4 * 4, E);
  scan_a<<<nb, SCAN_BLK, 0, stream>>>(in_cnt, rowptr + 1, bsums, N);
  scan_b<<<1, 256, 0, stream>>>(bsums, boff, nb);
  scan_c2<<<(N + 255) / 256, 256, 0, stream>>>(rowptr, boff, out_cnt, in_cnt,
                                               rowfin, nrm4, N);
  prescale_h<<<(N * 16 + R4 + 255) / 256, 256, 0, stream>>>(
      (const float4*)x, nrm4, xsh, (const float4*)relw, rwh, N * 16, R4);
  scatter_csr<<<(E4 + 255) / 256, 256, 0, stream>>>(
      (const int4*)src, (const int4*)dst, (const int4*)etype, (const int4*)rank,
      rowfin, ce, E4);
  if (Etail)
    scatter_tail<<<1, 64, 0, stream>>>(src, dst, etype, rank, rowfin, ce, E4 * 4, E);

  const int lblocks = (N + 3) / 4;
  selfloop_kernel<<<4096, 256, 0, stream>>>(xsh, w1, nrm4, y, N);
  layer_kernel<false><<<lblocks, 256, 0, stream>>>(xsh, y, rwh, rowfin, ce, nrm4,
                                                   (void*)h1h, N);
  selfloop_kernel<<<4096, 256, 0, stream>>>(h1h, w2, nrm4, y, N);
  layer_kernel<true><<<lblocks, 256, 0, stream>>>(h1h, y, rwh, rowfin, ce, nrm4,
                                                  d_out, N);
}